// Round 5
// baseline (1408.187 us; speedup 1.0000x reference)
//
#include <hip/hip_runtime.h>

#define N_NODES 50000
#define N_EDGES 800000
#define F 64
#define EDIM 16
#define NPB 32                       // dst nodes per block
#define NBLK ((N_NODES + NPB - 1) / NPB)   // 1563
#define TPB 256                      // 4 waves
#define NWAVE 4
#define NPW (NPB / NWAVE)            // 8 nodes per wave in node phase
#define NEG_SLOPE 0.01f

// ---------------- CSR build ----------------
__global__ __launch_bounds__(256) void hist_kernel(const int* __restrict__ ei,
                                                   int* __restrict__ count) {
    for (int e = blockIdx.x * blockDim.x + threadIdx.x; e < N_EDGES;
         e += gridDim.x * blockDim.x)
        atomicAdd(&count[ei[N_EDGES + e]], 1);
}

__global__ __launch_bounds__(1024) void scan_kernel(const int* __restrict__ count,
                                                    int* __restrict__ rowptr,
                                                    int* __restrict__ cursor) {
    __shared__ int buf[1024];
    const int tid = threadIdx.x;
    int run = 0;
    for (int base = 0; base < N_NODES; base += 1024) {
        int i = base + tid;
        int v = (i < N_NODES) ? count[i] : 0;
        buf[tid] = v;
        __syncthreads();
        for (int off = 1; off < 1024; off <<= 1) {
            int t = (tid >= off) ? buf[tid - off] : 0;
            __syncthreads();
            buf[tid] += t;
            __syncthreads();
        }
        int excl = buf[tid] - v;
        if (i < N_NODES) { rowptr[i] = run + excl; cursor[i] = run + excl; }
        run += buf[1023];
        __syncthreads();
    }
    if (tid == 0) rowptr[N_NODES] = run;
}

__global__ __launch_bounds__(256) void scatter_kernel(const int* __restrict__ ei,
                                                      int* __restrict__ cursor,
                                                      int2* __restrict__ pairsSD,
                                                      int* __restrict__ eid) {
    for (int e = blockIdx.x * blockDim.x + threadIdx.x; e < N_EDGES;
         e += gridDim.x * blockDim.x) {
        int s = ei[e];
        int d = ei[N_EDGES + e];
        int pos = atomicAdd(&cursor[d], 1);
        pairsSD[pos] = make_int2(s, d);
        eid[pos] = e;
    }
}

__global__ __launch_bounds__(256) void permute_kernel(const float4* __restrict__ ea4,
                                                      const int* __restrict__ eid,
                                                      float4* __restrict__ eaP) {
    int t = blockIdx.x * blockDim.x + threadIdx.x;
    if (t < N_EDGES * 4) {
        int j = t >> 2, c = t & 3;
        eaP[t] = ea4[((size_t)eid[j] << 2) + c];
    }
}

// ---------------- fuse readout weights ----------------
__global__ void fuse_weights_kernel(
    const float* __restrict__ W1, const float* __restrict__ b1,
    const float* __restrict__ W2, const float* __restrict__ b2,
    float* __restrict__ Wf, float* __restrict__ bf) {
    const int t = threadIdx.x;     // 128 threads
    const int i = t >> 1;
    const int j = t & 1;
    float acc = 0.f;
    for (int k = 0; k < 128; ++k) acc += W1[i * 128 + k] * W2[k * 2 + j];
    Wf[i * 2 + j] = acc;
    if (i == 0) {
        float accb = b2[j];
        for (int k = 0; k < 128; ++k) accb += b1[k] * W2[k * 2 + j];
        bf[j] = accb;
    }
}

// ---------------- fused GINE layer: pipelined edge loop + LDS node GEMM ----------------
template <bool LAST>
__global__ __launch_bounds__(TPB) void conv_kernel(
    const float* __restrict__ h,
    const int* __restrict__ rowptr,
    const int2* __restrict__ pairsSD,
    const int* __restrict__ eid,
    const float* __restrict__ eaSrc,
    const int usePerm,
    const float* __restrict__ We, const float* __restrict__ be,
    const float* __restrict__ Wn, const float* __restrict__ bn,
    const float* __restrict__ Wf, const float* __restrict__ bf,
    float* __restrict__ hout, float* __restrict__ out)
{
    __shared__ float aggrS[NPB * F];   // 8 KB
    __shared__ float WnS[F * F];       // 16 KB
    const int tid  = threadIdx.x;
    const int lane = tid & 63;
    const int wid  = tid >> 6;
    const int n0   = blockIdx.x * NPB;
    const int nCnt = min(NPB, N_NODES - n0);

    for (int i = tid; i < NPB * F; i += TPB) aggrS[i] = 0.f;
    {   // stage Wn in LDS once per block
        const float4* s4 = (const float4*)Wn;
        float4* d4 = (float4*)WnS;
        for (int i = tid; i < F * F / 4; i += TPB) d4[i] = s4[i];
    }

    float weR[EDIM];
#pragma unroll
    for (int k = 0; k < EDIM; ++k) weR[k] = We[k * F + lane];
    const float beR = be[lane];
    const float bnR = bn[lane];
    float wf0 = 0.f, wf1 = 0.f, bf0 = 0.f, bf1 = 0.f;
    if (LAST) { wf0 = Wf[lane * 2]; wf1 = Wf[lane * 2 + 1]; bf0 = bf[0]; bf1 = bf[1]; }

    __syncthreads();

    const int eBeg = rowptr[n0];
    const int eEnd = rowptr[n0 + nCnt];

    // ---- edge phase: depth-2 software pipeline ----
    int j = eBeg + wid;
    if (j < eEnd) {
        auto cl = [&](int x) { return x < eEnd ? x : eEnd - 1; };
        auto eaAt = [&](int jj) {
            return (const float4*)eaSrc + ((size_t)(usePerm ? jj : eid[jj]) << 2);
        };
        int2 sdA = pairsSD[j];
        int2 sdB = pairsSD[cl(j + NWAVE)];
        const float4* epA = eaAt(j);
        float4 a0 = epA[0], a1 = epA[1], a2 = epA[2], a3 = epA[3];
        float hsA = h[((size_t)sdA.x << 6) + lane];
        for (; j < eEnd; j += NWAVE) {
            const int jn  = cl(j + NWAVE);
            const int jnn = cl(j + 2 * NWAVE);
            // issue next iteration's loads first (independent of current compute)
            int2 sdC = pairsSD[jnn];
            float hsB = h[((size_t)sdB.x << 6) + lane];
            const float4* epB = eaAt(jn);
            float4 b0 = epB[0], b1 = epB[1], b2 = epB[2], b3 = epB[3];
            // compute current edge from registers
            float acc = beR;
            acc = fmaf(a0.x, weR[0],  acc); acc = fmaf(a0.y, weR[1],  acc);
            acc = fmaf(a0.z, weR[2],  acc); acc = fmaf(a0.w, weR[3],  acc);
            acc = fmaf(a1.x, weR[4],  acc); acc = fmaf(a1.y, weR[5],  acc);
            acc = fmaf(a1.z, weR[6],  acc); acc = fmaf(a1.w, weR[7],  acc);
            acc = fmaf(a2.x, weR[8],  acc); acc = fmaf(a2.y, weR[9],  acc);
            acc = fmaf(a2.z, weR[10], acc); acc = fmaf(a2.w, weR[11], acc);
            acc = fmaf(a3.x, weR[12], acc); acc = fmaf(a3.y, weR[13], acc);
            acc = fmaf(a3.z, weR[14], acc); acc = fmaf(a3.w, weR[15], acc);
            float m = fmaxf(hsA + acc, 0.f);                    // ReLU
            atomicAdd(&aggrS[((sdA.y - n0) << 6) + lane], m);   // ds_add_f32
            sdA = sdB; sdB = sdC; hsA = hsB;
            a0 = b0; a1 = b1; a2 = b2; a3 = b3;
        }
    }
    __syncthreads();

    // ---- t = h + aggr (in LDS) ----
    for (int nl = wid; nl < nCnt; nl += NWAVE)
        aggrS[(nl << 6) + lane] += h[((size_t)(n0 + nl) << 6) + lane];
    __syncthreads();

    // ---- node GEMM: 8 nodes per wave, Wn from LDS (read once), t via uniform b128 ----
    const int nlBeg = wid * NPW;
    float accv[NPW];
#pragma unroll
    for (int i = 0; i < NPW; ++i) accv[i] = bnR;
#pragma unroll
    for (int q = 0; q < 16; ++q) {
        float w0 = WnS[(4 * q + 0) * F + lane];
        float w1 = WnS[(4 * q + 1) * F + lane];
        float w2 = WnS[(4 * q + 2) * F + lane];
        float w3 = WnS[(4 * q + 3) * F + lane];
#pragma unroll
        for (int i = 0; i < NPW; ++i) {
            float4 t4 = *(const float4*)&aggrS[((nlBeg + i) << 6) + (q << 2)];
            accv[i] = fmaf(t4.x, w0, accv[i]);
            accv[i] = fmaf(t4.y, w1, accv[i]);
            accv[i] = fmaf(t4.z, w2, accv[i]);
            accv[i] = fmaf(t4.w, w3, accv[i]);
        }
    }
#pragma unroll
    for (int i = 0; i < NPW; ++i) {
        const int nl = nlBeg + i;
        if (nl >= nCnt) break;
        float acc = accv[i];
        acc = acc >= 0.f ? acc : NEG_SLOPE * acc;               // LeakyReLU
        if (!LAST) {
            hout[((size_t)(n0 + nl) << 6) + lane] = acc;
        } else {
            float v0 = acc * wf0, v1 = acc * wf1;
#pragma unroll
            for (int off = 32; off; off >>= 1) {
                v0 += __shfl_down(v0, off);
                v1 += __shfl_down(v1, off);
            }
            if (lane == 0) {
                out[(n0 + nl) * 2 + 0] = v0 + bf0;
                out[(n0 + nl) * 2 + 1] = v1 + bf1;
            }
        }
    }
}

extern "C" void kernel_launch(void* const* d_in, const int* in_sizes, int n_in,
                              void* d_out, int out_size, void* d_ws, size_t ws_size,
                              hipStream_t stream) {
    const float* x  = (const float*)d_in[0];
    const int*   ei = (const int*)d_in[1];
    const float* ea = (const float*)d_in[2];
    const float* Wn = (const float*)d_in[3];
    const float* bn = (const float*)d_in[4];
    const float* We = (const float*)d_in[5];     // [3,16,64]
    const float* be = (const float*)d_in[6];     // [3,64]
    const float* W1 = (const float*)d_in[7];
    const float* b1 = (const float*)d_in[8];
    const float* W2 = (const float*)d_in[9];
    const float* b2 = (const float*)d_in[10];
    float* out = (float*)d_out;

    size_t off = 0;
    char* base = (char*)d_ws;
    auto alloc = [&](size_t bytes) {
        off = (off + 15) & ~(size_t)15;
        char* p = base + off;
        off += bytes;
        return p;
    };
    int*   count   = (int*)alloc(sizeof(int) * N_NODES);
    int*   rowptr  = (int*)alloc(sizeof(int) * (N_NODES + 1));
    int*   cursor  = (int*)alloc(sizeof(int) * N_NODES);
    int2*  pairsSD = (int2*)alloc(sizeof(int2) * N_EDGES);
    int*   eid     = (int*)alloc(sizeof(int) * N_EDGES);
    float* hA      = (float*)alloc(sizeof(float) * (size_t)N_NODES * F);
    float* hB      = (float*)alloc(sizeof(float) * (size_t)N_NODES * F);
    float* Wf      = (float*)alloc(sizeof(float) * F * 2);
    float* bf      = (float*)alloc(sizeof(float) * 2);
    float* eaP     = (float*)alloc(sizeof(float) * (size_t)N_EDGES * EDIM);
    const int usePerm = (ws_size >= off) ? 1 : 0;

    fuse_weights_kernel<<<1, 128, 0, stream>>>(W1, b1, W2, b2, Wf, bf);

    // CSR build (edge_index is layer-invariant)
    hipMemsetAsync(count, 0, sizeof(int) * N_NODES, stream);
    hist_kernel<<<1024, 256, 0, stream>>>(ei, count);
    scan_kernel<<<1, 1024, 0, stream>>>(count, rowptr, cursor);
    scatter_kernel<<<1024, 256, 0, stream>>>(ei, cursor, pairsSD, eid);
    if (usePerm)
        permute_kernel<<<(N_EDGES * 4 + 255) / 256, 256, 0, stream>>>(
            (const float4*)ea, eid, (float4*)eaP);

    const float* eaSrc = usePerm ? eaP : ea;
    conv_kernel<false><<<NBLK, TPB, 0, stream>>>(x, rowptr, pairsSD, eid, eaSrc, usePerm,
        We + 0 * EDIM * F, be + 0 * F, Wn, bn, Wf, bf, hA, out);
    conv_kernel<false><<<NBLK, TPB, 0, stream>>>(hA, rowptr, pairsSD, eid, eaSrc, usePerm,
        We + 1 * EDIM * F, be + 1 * F, Wn, bn, Wf, bf, hB, out);
    conv_kernel<true><<<NBLK, TPB, 0, stream>>>(hB, rowptr, pairsSD, eid, eaSrc, usePerm,
        We + 2 * EDIM * F, be + 2 * F, Wn, bn, Wf, bf, nullptr, out);
}